// Round 10
// baseline (4656.241 us; speedup 1.0000x reference)
//
#include <hip/hip_runtime.h>
#include <hip/hip_bf16.h>
#include <math.h>

#define L 4096
#define D 512
#define PP 64
#define HH 128
#define EPSF 1e-8f

typedef _Float16 f16x8 __attribute__((ext_vector_type(8)));
typedef float f32x4 __attribute__((ext_vector_type(4)));

// ---------------- norms: ||p_l||, ||h_l|| ----------------
__global__ __launch_bounds__(64) void norms_kernel(const float* __restrict__ fp, const float* __restrict__ fh,
                                                   float* __restrict__ np_, float* __restrict__ nh_) {
  int b = blockIdx.x;
  int which = b >> 12;
  int l = b & (L - 1);
  const float* v = (which ? fh : fp) + (size_t)l * D;
  float s = 0.f;
  for (int i = threadIdx.x; i < D; i += 64) { float x = v[i]; s += x * x; }
  for (int off = 32; off > 0; off >>= 1) s += __shfl_down(s, off);
  if (threadIdx.x == 0) (which ? nh_ : np_)[l] = sqrtf(s);
}

// ---------------- att = (p @ h^T) / clamp(np*nh) ----------------
__global__ __launch_bounds__(256) void att_kernel(const float* __restrict__ A, const float* __restrict__ B,
                                                  const float* __restrict__ np_, const float* __restrict__ nh_,
                                                  float* __restrict__ att) {
  __shared__ float As[64][33];
  __shared__ float Bs[64][33];
  const int t = threadIdx.x;
  const int tc = t & 15, tr = t >> 4;
  const int row0 = blockIdx.y * 64, col0 = blockIdx.x * 64;
  float acc[4][4] = {};
  for (int k0 = 0; k0 < D; k0 += 32) {
#pragma unroll
    for (int i = 0; i < 2; i++) {
      int idx = t + i * 256;            // float4 idx in [0,512)
      int r = idx >> 3, c4 = idx & 7;
      float4 va = *reinterpret_cast<const float4*>(&A[(size_t)(row0 + r) * D + k0 + c4 * 4]);
      float4 vb = *reinterpret_cast<const float4*>(&B[(size_t)(col0 + r) * D + k0 + c4 * 4]);
      As[r][c4 * 4 + 0] = va.x; As[r][c4 * 4 + 1] = va.y; As[r][c4 * 4 + 2] = va.z; As[r][c4 * 4 + 3] = va.w;
      Bs[r][c4 * 4 + 0] = vb.x; Bs[r][c4 * 4 + 1] = vb.y; Bs[r][c4 * 4 + 2] = vb.z; Bs[r][c4 * 4 + 3] = vb.w;
    }
    __syncthreads();
#pragma unroll
    for (int kk = 0; kk < 32; kk++) {
      float a[4], bb[4];
#pragma unroll
      for (int i = 0; i < 4; i++) a[i] = As[tr * 4 + i][kk];
#pragma unroll
      for (int j = 0; j < 4; j++) bb[j] = Bs[tc * 4 + j][kk];
#pragma unroll
      for (int i = 0; i < 4; i++)
#pragma unroll
        for (int j = 0; j < 4; j++) acc[i][j] += a[i] * bb[j];
    }
    __syncthreads();
  }
#pragma unroll
  for (int i = 0; i < 4; i++) {
    int l = row0 + tr * 4 + i;
    float npl = np_[l];
#pragma unroll
    for (int j = 0; j < 4; j++) {
      int cjj = col0 + tc * 4 + j;
      float den = npl * nh_[cjj];
      den = den > EPSF ? den : EPSF;
      att[(size_t)l * L + cjj] = acc[i][j] / den;
    }
  }
}

// ---------------- row sums of att ----------------
__global__ __launch_bounds__(256) void rowsum_kernel(const float* __restrict__ att, float* __restrict__ rs) {
  int row = blockIdx.x;
  float s = 0.f;
  for (int c = threadIdx.x; c < L; c += 256) s += att[(size_t)row * L + c];
  for (int off = 32; off > 0; off >>= 1) s += __shfl_down(s, off);
  __shared__ float ps[4];
  if ((threadIdx.x & 63) == 0) ps[threadIdx.x >> 6] = s;
  __syncthreads();
  if (threadIdx.x == 0) rs[row] = ps[0] + ps[1] + ps[2] + ps[3];
}

// ---------------- column sums of att (2-stage, deterministic) ----------------
__global__ __launch_bounds__(256) void colpart_kernel(const float* __restrict__ att, float* __restrict__ pr) {
  int bx = blockIdx.x & 15, by = blockIdx.x >> 4;
  int col = bx * 256 + threadIdx.x;
  int r0 = by * 64;
  float s = 0.f;
#pragma unroll 8
  for (int r = 0; r < 64; r++) s += att[(size_t)(r0 + r) * L + col];
  pr[(size_t)by * L + col] = s;
}
__global__ __launch_bounds__(256) void colsum_kernel(const float* __restrict__ pr, float* __restrict__ cs) {
  int col = blockIdx.x * 256 + threadIdx.x;
  float s = 0.f;
#pragma unroll 8
  for (int k = 0; k < 64; k++) s += pr[(size_t)k * L + col];
  cs[col] = s;
}

// ---------------- att_mean_h = (att @ h) / clamp(rs) ----------------
__global__ __launch_bounds__(256) void amh_kernel(const float* __restrict__ att, const float* __restrict__ B,
                                                  const float* __restrict__ rs, float* __restrict__ outm) {
  __shared__ float As[64][33];
  __shared__ float Bs[32][65];
  const int t = threadIdx.x;
  const int tc = t & 15, tr = t >> 4;
  const int row0 = blockIdx.y * 64, col0 = blockIdx.x * 64;
  float acc[4][4] = {};
  for (int k0 = 0; k0 < L; k0 += 32) {
#pragma unroll
    for (int i = 0; i < 2; i++) {
      int idx = t + i * 256;
      int r = idx >> 3, c4 = idx & 7;
      float4 va = *reinterpret_cast<const float4*>(&att[(size_t)(row0 + r) * L + k0 + c4 * 4]);
      As[r][c4 * 4 + 0] = va.x; As[r][c4 * 4 + 1] = va.y; As[r][c4 * 4 + 2] = va.z; As[r][c4 * 4 + 3] = va.w;
      int rb = idx >> 4, cb4 = idx & 15;
      float4 vb = *reinterpret_cast<const float4*>(&B[(size_t)(k0 + rb) * D + col0 + cb4 * 4]);
      Bs[rb][cb4 * 4 + 0] = vb.x; Bs[rb][cb4 * 4 + 1] = vb.y; Bs[rb][cb4 * 4 + 2] = vb.z; Bs[rb][cb4 * 4 + 3] = vb.w;
    }
    __syncthreads();
#pragma unroll
    for (int kk = 0; kk < 32; kk++) {
      float a[4], bb[4];
#pragma unroll
      for (int i = 0; i < 4; i++) a[i] = As[tr * 4 + i][kk];
#pragma unroll
      for (int j = 0; j < 4; j++) bb[j] = Bs[kk][tc * 4 + j];
#pragma unroll
      for (int i = 0; i < 4; i++)
#pragma unroll
        for (int j = 0; j < 4; j++) acc[i][j] += a[i] * bb[j];
    }
    __syncthreads();
  }
#pragma unroll
  for (int i = 0; i < 4; i++) {
    int l = row0 + tr * 4 + i;
    float den = rs[l];
    den = den > EPSF ? den : EPSF;
#pragma unroll
    for (int j = 0; j < 4; j++)
      outm[(size_t)l * D + col0 + tc * 4 + j] = acc[i][j] / den;
  }
}

// ---------------- att_mean_p = (att^T @ p) / clamp(cs) ----------------
__global__ __launch_bounds__(256) void amp_kernel(const float* __restrict__ att, const float* __restrict__ B,
                                                  const float* __restrict__ cs, float* __restrict__ outm) {
  __shared__ float As[64][33];
  __shared__ float Bs[32][65];
  const int t = threadIdx.x;
  const int tc = t & 15, tr = t >> 4;
  const int row0 = blockIdx.y * 64, col0 = blockIdx.x * 64;
  float acc[4][4] = {};
  for (int k0 = 0; k0 < L; k0 += 32) {
#pragma unroll
    for (int i = 0; i < 8; i++) {
      int idx = t + i * 256;          // 2048 scalars, coalesced in 64-wide groups
      int k = idx >> 6, jj = idx & 63;
      As[jj][k] = att[(size_t)(k0 + k) * L + row0 + jj];
    }
#pragma unroll
    for (int i = 0; i < 2; i++) {
      int idx = t + i * 256;
      int rb = idx >> 4, cb4 = idx & 15;
      float4 vb = *reinterpret_cast<const float4*>(&B[(size_t)(k0 + rb) * D + col0 + cb4 * 4]);
      Bs[rb][cb4 * 4 + 0] = vb.x; Bs[rb][cb4 * 4 + 1] = vb.y; Bs[rb][cb4 * 4 + 2] = vb.z; Bs[rb][cb4 * 4 + 3] = vb.w;
    }
    __syncthreads();
#pragma unroll
    for (int kk = 0; kk < 32; kk++) {
      float a[4], bb[4];
#pragma unroll
      for (int i = 0; i < 4; i++) a[i] = As[tr * 4 + i][kk];
#pragma unroll
      for (int j = 0; j < 4; j++) bb[j] = Bs[kk][tc * 4 + j];
#pragma unroll
      for (int i = 0; i < 4; i++)
#pragma unroll
        for (int j = 0; j < 4; j++) acc[i][j] += a[i] * bb[j];
    }
    __syncthreads();
  }
#pragma unroll
  for (int i = 0; i < 4; i++) {
    int jrow = row0 + tr * 4 + i;
    float den = cs[jrow];
    den = den > EPSF ? den : EPSF;
#pragma unroll
    for (int j = 0; j < 4; j++)
      outm[(size_t)jrow * D + col0 + tc * 4 + j] = acc[i][j] / den;
  }
}

// ---------------- w2 transposed: w2t[d][p] = mp_w[p][d]^2 ----------------
__global__ void w2t_kernel(const float* __restrict__ mpw, float* __restrict__ w2t) {
  int o = blockIdx.x * blockDim.x + threadIdx.x;
  if (o >= PP * D) return;
  int dd = o >> 6, p = o & 63;
  float v = mpw[(size_t)p * D + dd];
  w2t[o] = v * v;
}

// ---------------- multi-perspective weighted cosine ----------------
__global__ __launch_bounds__(64) void match_kernel(const float* __restrict__ fp, const float* __restrict__ fh,
                                                   const float* __restrict__ amh, const float* __restrict__ amp,
                                                   const float* __restrict__ w2t,
                                                   float* __restrict__ match_p, float* __restrict__ match_h) {
  int b = blockIdx.x;
  int which = b >> 12;
  int l = b & (L - 1);
  const float* v1 = (which ? fh : fp) + (size_t)l * D;
  const float* v2 = (which ? amp : amh) + (size_t)l * D;
  __shared__ float s1[D], s2[D];
  int t = threadIdx.x;
#pragma unroll
  for (int i = 0; i < 2; i++) {
    int f4 = t + 64 * i;
    *reinterpret_cast<float4*>(&s1[f4 * 4]) = *reinterpret_cast<const float4*>(&v1[f4 * 4]);
    *reinterpret_cast<float4*>(&s2[f4 * 4]) = *reinterpret_cast<const float4*>(&v2[f4 * 4]);
  }
  __syncthreads();
  float num = 0.f, a1 = 0.f, a2 = 0.f;
  for (int dd = 0; dd < D; dd++) {
    float wv = w2t[dd * PP + t];
    float x = s1[dd], y = s2[dd];
    num += wv * x * y;
    a1 += wv * x * x;
    a2 += wv * y * y;
  }
  float n1 = fmaxf(sqrtf(a1), EPSF), n2 = fmaxf(sqrtf(a2), EPSF);
  float* outm = which ? match_h : match_p;
  outm[(size_t)l * PP + t] = num / (n1 * n2);
}

// ---------------- gx = match @ w_ih^T + (b_ih + b_hh), time-reversed for odd dirs ----------------
__global__ __launch_bounds__(512) void gx_kernel(const float* __restrict__ match_p, const float* __restrict__ match_h,
                                                 const float* __restrict__ wih_f, const float* __restrict__ wih_r,
                                                 const float* __restrict__ bih_f, const float* __restrict__ bhh_f,
                                                 const float* __restrict__ bih_r, const float* __restrict__ bhh_r,
                                                 float* __restrict__ gx) {
  int b = blockIdx.x;
  int dir = b >> 9;
  int chunk = b & 511;
  const float* m_src = (dir < 2) ? match_p : match_h;
  const float* wih = (dir & 1) ? wih_r : wih_f;
  const float* bi = (dir & 1) ? bih_r : bih_f;
  const float* bh = (dir & 1) ? bhh_r : bhh_f;
  __shared__ float m[8][PP];
  int t = threadIdx.x;
  {
    int tt = t >> 6, p = t & 63;
    int tstep = chunk * 8 + tt;
    int row = (dir & 1) ? (L - 1 - tstep) : tstep;
    m[tt][p] = m_src[(size_t)row * PP + p];
  }
  __syncthreads();
  int j = t;
  float bias = bi[j] + bh[j];
  float acc[8];
#pragma unroll
  for (int tt = 0; tt < 8; tt++) acc[tt] = bias;
  for (int p = 0; p < PP; p++) {
    float wv = wih[(size_t)j * PP + p];
#pragma unroll
    for (int tt = 0; tt < 8; tt++) acc[tt] += wv * m[tt][p];
  }
#pragma unroll
  for (int tt = 0; tt < 8; tt++)
    gx[((size_t)dir * L + chunk * 8 + tt) * 512 + j] = acc[tt];
}

// load 8 consecutive fp32 weights, convert+pack to f16x8 (MFMA A-fragment).
// The cvt/pack chain is NOT trivially rematerializable, so the packed values
// stay register-resident (r6 precedent: 32 packed weight VGPRs lived at
// VGPR_Count=52).
__device__ __forceinline__ f16x8 ldw(const float* p) {
  float4 a = *reinterpret_cast<const float4*>(p);
  float4 b = *reinterpret_cast<const float4*>(p + 4);
  f16x8 o;
  o[0] = (_Float16)a.x; o[1] = (_Float16)a.y; o[2] = (_Float16)a.z; o[3] = (_Float16)a.w;
  o[4] = (_Float16)b.x; o[5] = (_Float16)b.y; o[6] = (_Float16)b.z; o[7] = (_Float16)b.w;
  return o;
}

// ---------------- 4 sequential LSTMs — MFMA recurrent matvec ----------------
// ROUNDS 1-9 LESSON: the RA will not keep 64 fp32 weights/thread resident
// (spill/remat in every variant; ~2000 cyc/step of L2/scratch weight re-reads
// dominated). ROUND-10 FIX: move the matvec to the MFMA pipe.
// mfma_f32_16x16x32_f16: A = W fragment (16 outputs x 32 k), B = h in col 0
// (cols 1-15 zeroed), fp32 accumulate. Wave w, chains c in {0,1}: outputs
// jb = 32w+16c .. +15; chain = 4 MFMAs over k-chunks accumulating in one
// f32x4. Weights: 8 frags x 4 VGPR = 32 VGPR/thread of PACKED fp16 (the r6
// proven-resident footprint). Fragment maps (gfx950 16x16x32, C/D verified
// m89): A: row = lane&15, k = (lane>>4)*8 + e. B: col = lane&15, k likewise.
// D: col = lane&15, row = (lane>>4)*4 + reg -> col-0 lanes (l=0,16,32,48)
// hold z[jb + (l>>4)*4 + reg].
// Per step: 4 broadcast ds_read_b128 of h_pk -> zero-mask -> 2 independent
// 4-chains of MFMA -> col-0 lanes write raw z float4 -> barrier -> tid<128:
// z + gx (per-thread prefetched), 5 expf, c/h update, h -> fp16 ds_write_b16
// -> barrier. Precision regime = r6 (fp16 weights+h, fp32 accum): absmax
// 9.8e-4 vs 9.45e-3 threshold.
__global__ __attribute__((amdgpu_waves_per_eu(4, 4))) __launch_bounds__(1024)
void lstm_kernel(const float* __restrict__ gx,
                 const float* __restrict__ whh_f, const float* __restrict__ whh_r,
                 float* __restrict__ out) {
  const int dir = blockIdx.x;
  const float* __restrict__ whh = (dir & 1) ? whh_r : whh_f;
  const int tid = threadIdx.x;
  const int lane = tid & 63;
  const int wv = tid >> 6;            // wave 0..15
  const int r = lane & 15;            // A-row / D-col index
  const int ksub = lane >> 4;         // k subgroup 0..3
  const int jbA = wv * 32;            // chain-A output base
  const int jbB = wv * 32 + 16;       // chain-B output base

  const float* baseA = whh + (size_t)(jbA + r) * HH + ksub * 8;
  const float* baseB = whh + (size_t)(jbB + r) * HH + ksub * 8;
  f16x8 wA0 = ldw(baseA);       f16x8 wA1 = ldw(baseA + 32);
  f16x8 wA2 = ldw(baseA + 64);  f16x8 wA3 = ldw(baseA + 96);
  f16x8 wB0 = ldw(baseB);       f16x8 wB1 = ldw(baseB + 32);
  f16x8 wB2 = ldw(baseB + 64);  f16x8 wB3 = ldw(baseB + 96);

  __shared__ __align__(16) _Float16 h_pk[HH];   // 256 B
  __shared__ __align__(16) float z_s[512];
  if (tid < 64) reinterpret_cast<uint32_t*>(h_pk)[tid] = 0u;
  __syncthreads();

  const float* __restrict__ gsrc = gx + (size_t)dir * L * 512;
  const int m = tid & 127;
  const bool phaseB = (tid < HH);
  float c = 0.f, h = 0.f;
  float gi = 0.f, gf = 0.f, gg = 0.f, go = 0.f;
  if (phaseB) {
    gi = gsrc[m]; gf = gsrc[HH + m]; gg = gsrc[2 * HH + m]; go = gsrc[3 * HH + m];
  }
  const char* hp_base = reinterpret_cast<const char*>(h_pk) + ksub * 16;
  const bool col0 = (r == 0);

  for (int t = 0; t < L; t++) {
    // prefetch next step's gx (phase-B threads), hidden under MFMA phase
    float ni = 0.f, nf = 0.f, ng = 0.f, no = 0.f;
    if (phaseB && t + 1 < L) {
      const float* nb = gsrc + (size_t)(t + 1) * 512;
      ni = nb[m]; nf = nb[HH + m]; ng = nb[2 * HH + m]; no = nb[3 * HH + m];
    }
    f32x4 accA = {0.f, 0.f, 0.f, 0.f};
    f32x4 accB = {0.f, 0.f, 0.f, 0.f};
#define CHUNK(q, WA, WB)                                                        \
    {                                                                           \
      uint4 raw = *reinterpret_cast<const uint4*>(hp_base + (q) * 64);          \
      raw.x = col0 ? raw.x : 0u; raw.y = col0 ? raw.y : 0u;                     \
      raw.z = col0 ? raw.z : 0u; raw.w = col0 ? raw.w : 0u;                     \
      f16x8 bf = __builtin_bit_cast(f16x8, raw);                                \
      accA = __builtin_amdgcn_mfma_f32_16x16x32_f16(WA, bf, accA, 0, 0, 0);     \
      accB = __builtin_amdgcn_mfma_f32_16x16x32_f16(WB, bf, accB, 0, 0, 0);     \
    }
    CHUNK(0, wA0, wB0)
    CHUNK(1, wA1, wB1)
    CHUNK(2, wA2, wB2)
    CHUNK(3, wA3, wB3)
#undef CHUNK
    if (col0) {
      float4 zA; zA.x = accA[0]; zA.y = accA[1]; zA.z = accA[2]; zA.w = accA[3];
      float4 zB; zB.x = accB[0]; zB.y = accB[1]; zB.z = accB[2]; zB.w = accB[3];
      *reinterpret_cast<float4*>(&z_s[jbA + ksub * 4]) = zA;
      *reinterpret_cast<float4*>(&z_s[jbB + ksub * 4]) = zB;
    }
    __syncthreads();
    if (phaseB) {
      float zi = z_s[m] + gi;
      float zf = z_s[HH + m] + gf;
      float zg = z_s[2 * HH + m] + gg;
      float zo = z_s[3 * HH + m] + go;
      float iv = 1.f / (1.f + __expf(-zi));
      float fv = 1.f / (1.f + __expf(-zf));
      float eg = __expf(2.f * zg);
      float gvv = 1.f - 2.f / (eg + 1.f);
      float ov = 1.f / (1.f + __expf(-zo));
      c = fv * c + iv * gvv;
      float e2 = __expf(2.f * c);
      h = ov * (1.f - 2.f / (e2 + 1.f));
      h_pk[m] = (_Float16)h;
    }
    __syncthreads();
    gi = ni; gf = nf; gg = ng; go = no;
  }
  if (phaseB) out[dir * HH + tid] = h;
}

extern "C" void kernel_launch(void* const* d_in, const int* in_sizes, int n_in,
                              void* d_out, int out_size, void* d_ws, size_t ws_size,
                              hipStream_t stream) {
  const float* fp    = (const float*)d_in[0];
  const float* fh    = (const float*)d_in[1];
  const float* mpw   = (const float*)d_in[2];
  const float* wih_f = (const float*)d_in[3];
  const float* whh_f = (const float*)d_in[4];
  const float* bih_f = (const float*)d_in[5];
  const float* bhh_f = (const float*)d_in[6];
  const float* wih_r = (const float*)d_in[7];
  const float* whh_r = (const float*)d_in[8];
  const float* bih_r = (const float*)d_in[9];
  const float* bhh_r = (const float*)d_in[10];
  float* out = (float*)d_out;
  float* ws = (float*)d_ws;

  // workspace layout (floats)
  size_t np_off  = 0;                       // 4096
  size_t nh_off  = np_off + L;              // 4096
  size_t rs_off  = nh_off + L;              // 4096
  size_t cs_off  = rs_off + L;              // 4096
  size_t w2_off  = cs_off + L;              // 32768
  size_t amh_off = w2_off + (size_t)PP * D; // 2097152
  size_t amp_off = amh_off + (size_t)L * D; // 2097152
  size_t mp_off  = amp_off + (size_t)L * D; // 262144
  size_t mh_off  = mp_off + (size_t)L * PP; // 262144
  size_t pr_off  = mh_off + (size_t)L * PP; // 262144 (64 x 4096)
  size_t att_off = pr_off + (size_t)64 * L; // 16777216
  size_t gx_off  = att_off;                 // alias: gx (8388608) reuses dead att region
  size_t total   = att_off + (size_t)L * L;
  if (ws_size < total * sizeof(float)) return;  // workspace too small — bail safely

  float* np_  = ws + np_off;
  float* nh_  = ws + nh_off;
  float* rs   = ws + rs_off;
  float* cs   = ws + cs_off;
  float* w2t  = ws + w2_off;
  float* amh  = ws + amh_off;
  float* amp  = ws + amp_off;
  float* mtp  = ws + mp_off;
  float* mth  = ws + mh_off;
  float* pr   = ws + pr_off;
  float* att  = ws + att_off;
  float* gx   = ws + gx_off;

  norms_kernel<<<2 * L, 64, 0, stream>>>(fp, fh, np_, nh_);
  att_kernel<<<dim3(64, 64), 256, 0, stream>>>(fp, fh, np_, nh_, att);
  rowsum_kernel<<<L, 256, 0, stream>>>(att, rs);
  colpart_kernel<<<1024, 256, 0, stream>>>(att, pr);
  colsum_kernel<<<16, 256, 0, stream>>>(pr, cs);
  amh_kernel<<<dim3(8, 64), 256, 0, stream>>>(att, fh, rs, amh);
  amp_kernel<<<dim3(8, 64), 256, 0, stream>>>(att, fp, cs, amp);
  w2t_kernel<<<(PP * D + 255) / 256, 256, 0, stream>>>(mpw, w2t);
  match_kernel<<<2 * L, 64, 0, stream>>>(fp, fh, amh, amp, w2t, mtp, mth);
  gx_kernel<<<4 * (L / 8), 512, 0, stream>>>(mtp, mth, wih_f, wih_r, bih_f, bhh_f, bih_r, bhh_r, gx);
  lstm_kernel<<<4, 1024, 0, stream>>>(gx, whh_f, whh_r, out);
}